// Round 1
// baseline (1661.064 us; speedup 1.0000x reference)
//
#include <hip/hip_runtime.h>

// Fixed problem shape from setup_inputs(): x = (16, 64, 512, 512) fp32.
// Output: (LL, LH, HL, HH) each (16, 64, 256, 256) fp32, concatenated flat.

#define W_IN   512
#define H_IN   512
#define PLANES (16 * 64)
#define OW     (W_IN / 2)                 // 256
#define OH     (H_IN / 2)                 // 256

__global__ __launch_bounds__(256) void haar2d_kernel(const float* __restrict__ x,
                                                     float* __restrict__ out) {
    const long long N        = (long long)PLANES * H_IN * W_IN;    // 268435456
    const long long SUB      = N >> 2;                             // 67108864 per subband
    const long long IN_PLANE = (long long)H_IN * W_IN;             // 262144
    const long long OUT_PLANE = (long long)OH * OW;                // 65536

    long long tid = (long long)blockIdx.x * blockDim.x + threadIdx.x;

    // thread -> (plane, oh, column-group of 4 output cols)
    int cg = (int)(tid & 63);          // 64 groups of 4 output cols per row
    long long t = tid >> 6;
    int oh = (int)(t & (OH - 1));
    long long plane = t >> 8;

    const float* row0 = x + plane * IN_PLANE + (long long)(2 * oh) * W_IN + cg * 8;
    const float* row1 = row0 + W_IN;

    float4 r0a = *(const float4*)(row0);
    float4 r0b = *(const float4*)(row0 + 4);
    float4 r1a = *(const float4*)(row1);
    float4 r1b = *(const float4*)(row1 + 4);

    float4 LL, LH, HL, HH;

    // j = 0: a=r0a.x b=r0a.y c=r1a.x d=r1a.y
    {
        float apb = r0a.x + r0a.y, amb = r0a.x - r0a.y;
        float cpd = r1a.x + r1a.y, cmd = r1a.x - r1a.y;
        LL.x = 0.5f * (apb + cpd);
        LH.x = 0.5f * (amb + cmd);
        HL.x = 0.5f * (apb - cpd);
        HH.x = 0.5f * (amb - cmd);
    }
    // j = 1: a=r0a.z b=r0a.w c=r1a.z d=r1a.w
    {
        float apb = r0a.z + r0a.w, amb = r0a.z - r0a.w;
        float cpd = r1a.z + r1a.w, cmd = r1a.z - r1a.w;
        LL.y = 0.5f * (apb + cpd);
        LH.y = 0.5f * (amb + cmd);
        HL.y = 0.5f * (apb - cpd);
        HH.y = 0.5f * (amb - cmd);
    }
    // j = 2: a=r0b.x b=r0b.y c=r1b.x d=r1b.y
    {
        float apb = r0b.x + r0b.y, amb = r0b.x - r0b.y;
        float cpd = r1b.x + r1b.y, cmd = r1b.x - r1b.y;
        LL.z = 0.5f * (apb + cpd);
        LH.z = 0.5f * (amb + cmd);
        HL.z = 0.5f * (apb - cpd);
        HH.z = 0.5f * (amb - cmd);
    }
    // j = 3: a=r0b.z b=r0b.w c=r1b.z d=r1b.w
    {
        float apb = r0b.z + r0b.w, amb = r0b.z - r0b.w;
        float cpd = r1b.z + r1b.w, cmd = r1b.z - r1b.w;
        LL.w = 0.5f * (apb + cpd);
        LH.w = 0.5f * (amb + cmd);
        HL.w = 0.5f * (apb - cpd);
        HH.w = 0.5f * (amb - cmd);
    }

    long long obase = plane * OUT_PLANE + (long long)oh * OW + cg * 4;
    *(float4*)(out + obase)            = LL;
    *(float4*)(out + SUB + obase)      = LH;
    *(float4*)(out + 2 * SUB + obase)  = HL;
    *(float4*)(out + 3 * SUB + obase)  = HH;
}

extern "C" void kernel_launch(void* const* d_in, const int* in_sizes, int n_in,
                              void* d_out, int out_size, void* d_ws, size_t ws_size,
                              hipStream_t stream) {
    const float* x = (const float*)d_in[0];
    float* out = (float*)d_out;

    // total threads = N/16 (each thread: 16 input floats -> 16 output floats)
    const long long n_threads = ((long long)PLANES * H_IN * W_IN) / 16; // 16,777,216
    const int block = 256;
    const long long grid = n_threads / block;                           // 65,536

    haar2d_kernel<<<(dim3)(unsigned)grid, block, 0, stream>>>(x, out);
}